// Round 7
// baseline (352.163 us; speedup 1.0000x reference)
//
#include <hip/hip_runtime.h>
#include <hip/hip_bf16.h>
#include <math.h>

typedef __hip_bfloat16 bf16;
typedef __attribute__((ext_vector_type(8))) short short8;
typedef __attribute__((ext_vector_type(4))) float floatx4;
typedef __attribute__((ext_vector_type(16))) float floatx16;

__device__ __forceinline__ void async_copy16(const void* gptr, void* lptr) {
  __builtin_amdgcn_global_load_lds(
      (const __attribute__((address_space(1))) unsigned int*)gptr,
      (__attribute__((address_space(3))) unsigned int*)lptr,
      16, 0, 0);
}

__device__ __forceinline__ unsigned int f2bf_bits(float x) {
  bf16 h = __float2bfloat16(x);
  return (unsigned int)*reinterpret_cast<unsigned short*>(&h);
}

__device__ __forceinline__ float bfbits2f(unsigned int u) {
  unsigned v = u << 16;
  return *reinterpret_cast<float*>(&v);
}

__device__ __forceinline__ floatx4 mfma16(short8 a, short8 b, floatx4 c) {
  return __builtin_amdgcn_mfma_f32_16x16x32_bf16(a, b, c, 0, 0, 0);
}

// flag = 1 -> fp32 inputs, 0 -> bf16 inputs.
__global__ void dtype_sniff(const unsigned int* __restrict__ u, int* __restrict__ flag) {
  __shared__ int cnt[256];
  const int tid = threadIdx.x;
  const unsigned v = u[tid * 16];
  const int e = (v >> 7) & 0xFF;
  cnt[tid] = (e >= 90 && e <= 140) ? 1 : 0;
  __syncthreads();
  for (int s = 128; s > 0; s >>= 1) {
    if (tid < s) cnt[tid] += cnt[tid + s];
    __syncthreads();
  }
  if (tid == 0) flag[0] = (cnt[0] >= 192) ? 0 : 1;
}

// One kernel converting all inputs to bf16 (fp32 src if *flag else bf16 copy).
__global__ void conv_all(const void* hs, const void* wq, const void* wk, const void* wv,
                         const void* wo, const void* bq, const void* bk, const void* bv,
                         bf16* hsb, bf16* wqb, bf16* wkb, bf16* wvb, bf16* wob, bf16* b3,
                         long nhs4, const int* __restrict__ flag) {
  const bool f = (*flag != 0);
  const long W4 = 1048576, KV4 = 262144;  // H*H/4, KV*H/4
  const long total = nhs4 + W4 + 2 * KV4 + W4 + 512 + 128 + 128;
  const long stride = (long)gridDim.x * blockDim.x;
  for (long i = (long)blockIdx.x * blockDim.x + threadIdx.x; i < total; i += stride) {
    const void* src;
    bf16* dst;
    long off, j = i;
    if (j < nhs4) { src = hs; dst = hsb; off = j; }
    else if ((j -= nhs4) < W4) { src = wq; dst = wqb; off = j; }
    else if ((j -= W4) < KV4) { src = wk; dst = wkb; off = j; }
    else if ((j -= KV4) < KV4) { src = wv; dst = wvb; off = j; }
    else if ((j -= KV4) < W4) { src = wo; dst = wob; off = j; }
    else if ((j -= W4) < 512) { src = bq; dst = b3; off = j; }
    else if ((j -= 512) < 128) { src = bk; dst = b3 + 2048; off = j; }
    else { j -= 128; src = bv; dst = b3 + 2560; off = j; }
    uint2 o;
    if (f) {
      float4 v = ((const float4*)src)[off];
      o.x = f2bf_bits(v.x) | (f2bf_bits(v.y) << 16);
      o.y = f2bf_bits(v.z) | (f2bf_bits(v.w) << 16);
    } else {
      o = ((const uint2*)src)[off];
    }
    ((uint2*)dst)[off] = o;
  }
}

// ---------------------------------------------------------------------------
// m97-structure 128x128 GEMM core (4 waves, 256 thr).
// R7: BK=32 (parameter change inside the verified T3 2-phase template).
// LDS = 2 x 8KB x 2 operands = 32 KB -> 4 blocks/CU: the 768-block qkv grid
// is fully resident in one dispatch round (was 1.5 rounds at 64 KB / 2
// blocks/CU), and cross-block overlap hides the per-barrier drain (m114).
//   prologue: STAGE(buf0, 0); __syncthreads
//   loop t:   STAGE(buf^1, t+1) -- flies under the MFMA cluster
//             ds_read buf[cur]; 16x MFMA; __syncthreads
// Swizzle for 4 k-slots/row: row base bank = 16*(R&1); XOR slot with
// ((R>>1)&3) -> exactly 2-way bank aliasing (free, m136).  Applied as linear
// LDS dest + inverse-swizzled GLOBAL source + swizzled ds_read (rule #21).
// ---------------------------------------------------------------------------

// Fused QKV GEMM + RoPE.  Q->Qb [M,2048] (rotated), K->Kb [M,512] (rotated),
// V->Vt [B,4,128,S] transposed.  bias3 = bq|bk|bv.
__global__ __launch_bounds__(256) void qkv_gemm(const bf16* __restrict__ A,
                                                const bf16* __restrict__ wq,
                                                const bf16* __restrict__ wk,
                                                const bf16* __restrict__ wv,
                                                const bf16* __restrict__ bias3,
                                                bf16* __restrict__ Qb,
                                                bf16* __restrict__ Kb,
                                                bf16* __restrict__ Vt,
                                                const int* __restrict__ pos_ids,
                                                int M, int K, int S) {
  __shared__ __align__(16) short lA[2 * 4096];  // 2 x 8 KB
  __shared__ __align__(16) short lB[2 * 4096];  // 2 x 8 KB
  const int tid = threadIdx.x;
  const int wave = tid >> 6;
  const int lane = tid & 63;
  const int lrow = lane & 15;
  const int quad = lane >> 4;
  const int m0 = blockIdx.y * 128;
  const int n0 = blockIdx.x * 128;
  const int wm = (wave & 1) * 64;
  const int wn = (wave >> 1) * 64;
  const int srow = tid >> 2;   // [0,64) staging row within pass
  const int sslot = tid & 3;   // 16B k-slot

  const bf16* Wr;
  int nloc;
  if (n0 < 2048) { Wr = wq; nloc = n0; }
  else if (n0 < 2560) { Wr = wk; nloc = n0 - 2048; }
  else { Wr = wv; nloc = n0 - 2560; }

  auto stage = [&](int buf, int k0) {
#pragma unroll
    for (int p = 0; p < 2; ++p) {
      const int row = p * 64 + srow;
      const int gk = k0 + ((sslot ^ ((row >> 1) & 3)) << 3);  // inverse-swizzled
      async_copy16(A + (size_t)(m0 + row) * K + gk,
                   &lA[buf * 4096 + p * 2048 + wave * 512]);
      async_copy16(Wr + (size_t)(nloc + row) * K + gk,
                   &lB[buf * 4096 + p * 2048 + wave * 512]);
    }
  };

  const int nt = K >> 5;
  floatx4 acc[4][4] = {};

  stage(0, 0);
  __syncthreads();
  for (int t = 0; t < nt; ++t) {
    const int cur = t & 1;
    if (t + 1 < nt) stage(cur ^ 1, (t + 1) << 5);
    const short* sA = &lA[cur * 4096];
    const short* sB = &lB[cur * 4096];
    short8 af[4], bfr[4];
#pragma unroll
    for (int i = 0; i < 4; ++i) {
      const int R = wm + i * 16 + lrow;
      af[i] = *(const short8*)&sA[R * 32 + ((quad ^ ((R >> 1) & 3)) << 3)];
    }
#pragma unroll
    for (int j = 0; j < 4; ++j) {
      const int R = wn + j * 16 + lrow;
      bfr[j] = *(const short8*)&sB[R * 32 + ((quad ^ ((R >> 1) & 3)) << 3)];
    }
#pragma unroll
    for (int i = 0; i < 4; ++i)
#pragma unroll
      for (int j = 0; j < 4; ++j)
        acc[i][j] = mfma16(af[i], bfr[j], acc[i][j]);
    __syncthreads();  // drains t+1 staging; buf[cur] fully consumed
  }

  if (n0 < 2560) {
    // Q or K: fused RoPE.  Partner wave = wave^2 (wn flipped by 64).
    short* exch = lA;  // 10 KB needed, 16 KB available
    const int myid = wave * 64 + lane;
    const int pid = (wave ^ 2) * 64 + lane;
    float pos[16];
#pragma unroll
    for (int i = 0; i < 4; ++i)
#pragma unroll
      for (int r = 0; r < 4; ++r)
        pos[i * 4 + r] = (float)pos_ids[m0 + wm + i * 16 + quad * 4 + r];
#pragma unroll
    for (int j = 0; j < 4; ++j) {
      const int col = n0 + wn + j * 16 + lrow;
      const float bv = __bfloat162float(bias3[col]);
      unsigned ob[16];
#pragma unroll
      for (int i = 0; i < 4; ++i)
#pragma unroll
        for (int r = 0; r < 4; ++r)
          ob[i * 4 + r] = f2bf_bits(acc[i][j][r] + bv);
      __syncthreads();  // previous round's reads (or main loop) done
#pragma unroll
      for (int k = 0; k < 4; ++k) {
        uint2 w;
        w.x = ob[4 * k + 0] | (ob[4 * k + 1] << 16);
        w.y = ob[4 * k + 2] | (ob[4 * k + 3] << 16);
        *(uint2*)&exch[myid * 20 + k * 4] = w;
      }
      __syncthreads();
      unsigned pb[16];
#pragma unroll
      for (int k = 0; k < 4; ++k) {
        const uint2 w = *(const uint2*)&exch[pid * 20 + k * 4];
        pb[4 * k + 0] = w.x & 0xffff; pb[4 * k + 1] = w.x >> 16;
        pb[4 * k + 2] = w.y & 0xffff; pb[4 * k + 3] = w.y >> 16;
      }
      const int d = col & 127;
      const float fr = exp2f((float)(d & 63) * -0.31143075889569023f);
      const float sgn = (d < 64) ? -1.0f : 1.0f;
      bf16* dst;
      int ldc, ccol;
      if (n0 < 2048) { dst = Qb; ldc = 2048; ccol = col; }
      else { dst = Kb; ldc = 512; ccol = col - 2048; }
#pragma unroll
      for (int i = 0; i < 4; ++i)
#pragma unroll
        for (int r = 0; r < 4; ++r) {
          float sn, cs;
          __sincosf(pos[i * 4 + r] * fr, &sn, &cs);
          const float v = bfbits2f(ob[i * 4 + r]);
          const float pv = bfbits2f(pb[i * 4 + r]);
          const int row = m0 + wm + i * 16 + quad * 4 + r;
          dst[(size_t)row * ldc + ccol] = __float2bfloat16(v * cs + sgn * pv * sn);
        }
    }
  } else {
    // V path: bias + transpose-store, no RoPE.
#pragma unroll
    for (int j = 0; j < 4; ++j) {
      const int col = n0 + wn + j * 16 + lrow;
      const float bv = __bfloat162float(bias3[col]);
#pragma unroll
      for (int i = 0; i < 4; ++i) {
        const int row = m0 + wm + i * 16 + quad * 4;
        const int dcol = col - 2560;
        const int kvh = dcol >> 7, d = dcol & 127;
        const int bb = row / S, s = row % S;
        uint2 pk;
        pk.x = f2bf_bits(acc[i][j][0] + bv) | (f2bf_bits(acc[i][j][1] + bv) << 16);
        pk.y = f2bf_bits(acc[i][j][2] + bv) | (f2bf_bits(acc[i][j][3] + bv) << 16);
        *(uint2*)&Vt[((size_t)(bb * 4 + kvh) * 128 + d) * S + s] = pk;
      }
    }
  }
}

// O-proj GEMM (same 2-phase BK=32 core): out fp32 if *flag else bf16.
__global__ __launch_bounds__(256) void gemm_o(const bf16* __restrict__ A,
                                              const bf16* __restrict__ W,
                                              void* __restrict__ C,
                                              int M, int N, int K,
                                              const int* __restrict__ flag) {
  __shared__ __align__(16) short lA[2 * 4096];
  __shared__ __align__(16) short lB[2 * 4096];
  const int tid = threadIdx.x;
  const int wave = tid >> 6;
  const int lane = tid & 63;
  const int lrow = lane & 15;
  const int quad = lane >> 4;
  const int m0 = blockIdx.y * 128;
  const int n0 = blockIdx.x * 128;
  const int wm = (wave & 1) * 64;
  const int wn = (wave >> 1) * 64;
  const int srow = tid >> 2;
  const int sslot = tid & 3;
  const bool of32 = (*flag != 0);

  auto stage = [&](int buf, int k0) {
#pragma unroll
    for (int p = 0; p < 2; ++p) {
      const int row = p * 64 + srow;
      const int gk = k0 + ((sslot ^ ((row >> 1) & 3)) << 3);
      async_copy16(A + (size_t)(m0 + row) * K + gk,
                   &lA[buf * 4096 + p * 2048 + wave * 512]);
      async_copy16(W + (size_t)(n0 + row) * K + gk,
                   &lB[buf * 4096 + p * 2048 + wave * 512]);
    }
  };

  const int nt = K >> 5;
  floatx4 acc[4][4] = {};

  stage(0, 0);
  __syncthreads();
  for (int t = 0; t < nt; ++t) {
    const int cur = t & 1;
    if (t + 1 < nt) stage(cur ^ 1, (t + 1) << 5);
    const short* sA = &lA[cur * 4096];
    const short* sB = &lB[cur * 4096];
    short8 af[4], bfr[4];
#pragma unroll
    for (int i = 0; i < 4; ++i) {
      const int R = wm + i * 16 + lrow;
      af[i] = *(const short8*)&sA[R * 32 + ((quad ^ ((R >> 1) & 3)) << 3)];
    }
#pragma unroll
    for (int j = 0; j < 4; ++j) {
      const int R = wn + j * 16 + lrow;
      bfr[j] = *(const short8*)&sB[R * 32 + ((quad ^ ((R >> 1) & 3)) << 3)];
    }
#pragma unroll
    for (int i = 0; i < 4; ++i)
#pragma unroll
      for (int j = 0; j < 4; ++j)
        acc[i][j] = mfma16(af[i], bfr[j], acc[i][j]);
    __syncthreads();
  }

#pragma unroll
  for (int j = 0; j < 4; ++j) {
    const int col = n0 + wn + j * 16 + lrow;
#pragma unroll
    for (int i = 0; i < 4; ++i) {
      const int row = m0 + wm + i * 16 + quad * 4;
#pragma unroll
      for (int r = 0; r < 4; ++r) {
        const size_t idx = (size_t)(row + r) * N + col;
        if (of32) ((float*)C)[idx] = acc[i][j][r];
        else ((bf16*)C)[idx] = __float2bfloat16(acc[i][j][r]);
      }
    }
  }
}

// Flash attention, 32x32x16 MFMA, single-barrier double-buffered pipeline.
// Block = 128 q x one (b,h); 4 waves, wave owns 32 q-cols.  BKV=64.
// K/V fragment-order staging (HW-verified layouts).  Q in registers.
// qt pairing (y<8 ? y : 23-y) balances per-CU work under mod-256 round-robin
// dispatch: resident pairs (qt, 15-qt) sum to 36 iters each.
// P kept in-register (T12) via v_permlane32_swap_b32; defer-rescale THR=0.
// (R7: byte-exact revert to the R5 version -- R6's setprio/raw-units edits
// regressed; setprio's prerequisite is per-CU phase diversity, not the
// 4-wave lockstep here.)
__global__ __launch_bounds__(256, 2) void flash_attn(const bf16* Q,
                                                     const bf16* __restrict__ K,
                                                     const bf16* __restrict__ Vt,
                                                     bf16* O, int S) {
  __shared__ __align__(16) short lK[2][16 * 512];  // 2 x 16 KB
  __shared__ __align__(16) short lV[2][16 * 512];  // 2 x 16 KB

  const int tid = threadIdx.x;
  const int wave = tid >> 6;
  const int lane = tid & 63;
  const int l31 = lane & 31;
  const int half = lane >> 5;
  const int bh = blockIdx.x;
  const int y = blockIdx.y;
  const int qt = (y < 8) ? y : 23 - y;
  const int q0 = qt * 128;
  const int b = bh >> 4;
  const int h = bh & 15;
  const int kvh = h >> 2;
  const int wq0 = wave * 32;
  const int q_g = q0 + wq0 + l31;

  short8 qf[8];
  {
    const bf16* qbase = Q + ((size_t)(b * S + q_g) * 16 + h) * 128 + half * 8;
#pragma unroll
    for (int ks = 0; ks < 8; ++ks)
      qf[ks] = *(const short8*)(qbase + ks * 16);
  }

  floatx16 acc[4] = {};
  float m_i = -1.0e30f, l_i = 0.0f;
  const float scale = 0.08838834764831845f;
  const int fk0 = wave * 4;
  const int niter = 2 * qt + 2;

  auto stage = [&](int buf, int kv0) {
#pragma unroll
    for (int i = 0; i < 4; ++i) {
      const int fk = fk0 + i;
      const int mt = fk & 1, kstep = fk >> 1;
      async_copy16(K + ((size_t)(b * S + kv0 + mt * 32 + l31) * 4 + kvh) * 128 + kstep * 16 + half * 8,
                   &lK[buf][fk * 512]);
      const int kvs = fk >> 2, mtd = fk & 3;
      async_copy16(Vt + ((size_t)(b * 4 + kvh) * 128 + mtd * 32 + l31) * S + kv0 + kvs * 16 + half * 8,
                   &lV[buf][fk * 512]);
    }
  };

  stage(0, 0);  // prefetch

  for (int it = 0; it < niter; ++it) {
    const int kv0 = it * 64;
    const int cur = it & 1;
    __syncthreads();  // drains DMA(cur) issued one iter ago; frees buf cur^1
    if (it + 1 < niter) stage(cur ^ 1, kv0 + 64);

    // S^T = K·Q^T  (C: col = q = l31, row = kv = mt*32 + (r&3)+8*(r>>2)+4*half)
    floatx16 st[2] = {};
#pragma unroll
    for (int ks = 0; ks < 8; ++ks) {
      short8 k0 = *(const short8*)&lK[cur][(ks * 2 + 0) * 512 + lane * 8];
      short8 k1 = *(const short8*)&lK[cur][(ks * 2 + 1) * 512 + lane * 8];
      st[0] = __builtin_amdgcn_mfma_f32_32x32x16_bf16(k0, qf[ks], st[0], 0, 0, 0);
      st[1] = __builtin_amdgcn_mfma_f32_32x32x16_bf16(k1, qf[ks], st[1], 0, 0, 0);
    }

    float mx = -1.0e30f;
    if (kv0 + 63 > q0 + wq0) {
#pragma unroll
      for (int r = 0; r < 16; ++r) {
        const int kv_l = kv0 + (r & 3) + 8 * (r >> 2) + 4 * half;
        float v0 = st[0][r] * scale;
        v0 = (kv_l > q_g) ? -1.0e9f : v0;
        float v1 = st[1][r] * scale;
        v1 = (kv_l + 32 > q_g) ? -1.0e9f : v1;
        st[0][r] = v0; st[1][r] = v1;
        mx = fmaxf(mx, fmaxf(v0, v1));
      }
    } else {
#pragma unroll
      for (int r = 0; r < 16; ++r) {
        const float v0 = st[0][r] * scale;
        const float v1 = st[1][r] * scale;
        st[0][r] = v0; st[1][r] = v1;
        mx = fmaxf(mx, fmaxf(v0, v1));
      }
    }
    mx = fmaxf(mx, __shfl_xor(mx, 32));
    if (!__all(mx <= m_i)) {  // defer-rescale THR=0 (bit-identical)
      const float mnew = fmaxf(m_i, mx);
      const float alpha = __expf(m_i - mnew);
      m_i = mnew;
      l_i *= alpha;
#pragma unroll
      for (int t = 0; t < 4; ++t)
#pragma unroll
        for (int r = 0; r < 16; ++r) acc[t][r] *= alpha;
    }
    float rs = 0.0f;
#pragma unroll
    for (int r = 0; r < 16; ++r) {
      const float p0 = __expf(st[0][r] - m_i);
      const float p1 = __expf(st[1][r] - m_i);
      st[0][r] = p0; st[1][r] = p1;
      rs += p0 + p1;
    }
    rs += __shfl_xor(rs, 32);
    l_i += rs;

    // P -> PV B-fragments in-register (T12) via v_permlane32_swap_b32.
#pragma unroll
    for (int kvs = 0; kvs < 4; ++kvs) {
      const int cLo = 2 * kvs, cHi = cLo + 1;
      const int mtL = cLo >> 2, gL = cLo & 3;
      const int mtH = cHi >> 2, gH = cHi & 3;
      unsigned a0 = f2bf_bits(st[mtL][4 * gL + 0]) | (f2bf_bits(st[mtL][4 * gL + 1]) << 16);
      unsigned a1 = f2bf_bits(st[mtL][4 * gL + 2]) | (f2bf_bits(st[mtL][4 * gL + 3]) << 16);
      unsigned b0 = f2bf_bits(st[mtH][4 * gH + 0]) | (f2bf_bits(st[mtH][4 * gH + 1]) << 16);
      unsigned b1 = f2bf_bits(st[mtH][4 * gH + 2]) | (f2bf_bits(st[mtH][4 * gH + 3]) << 16);
      asm("v_permlane32_swap_b32 %0, %1" : "+v"(a0), "+v"(b0));
      asm("v_permlane32_swap_b32 %0, %1" : "+v"(a1), "+v"(b1));
      union { unsigned u[4]; short8 s; } pu;
      pu.u[0] = a0; pu.u[1] = a1; pu.u[2] = b0; pu.u[3] = b1;
      const short8 pf = pu.s;
#pragma unroll
      for (int mtd = 0; mtd < 4; ++mtd) {
        short8 vf = *(const short8*)&lV[cur][(kvs * 4 + mtd) * 512 + lane * 8];
        acc[mtd] = __builtin_amdgcn_mfma_f32_32x32x16_bf16(vf, pf, acc[mtd], 0, 0, 0);
      }
    }
  }

  const float inv_l = 1.0f / l_i;
  bf16* obase = O + ((size_t)(b * S + q_g) * 16 + h) * 128;
#pragma unroll
  for (int mtd = 0; mtd < 4; ++mtd)
#pragma unroll
    for (int g = 0; g < 4; ++g) {
      uint2 pk;
      pk.x = f2bf_bits(acc[mtd][4 * g] * inv_l) | (f2bf_bits(acc[mtd][4 * g + 1] * inv_l) << 16);
      pk.y = f2bf_bits(acc[mtd][4 * g + 2] * inv_l) | (f2bf_bits(acc[mtd][4 * g + 3] * inv_l) << 16);
      *(uint2*)(obase + mtd * 32 + 8 * g + 4 * half) = pk;
    }
}

extern "C" void kernel_launch(void* const* d_in, const int* in_sizes, int n_in,
                              void* d_out, int out_size, void* d_ws, size_t ws_size,
                              hipStream_t stream) {
  const void* hs = d_in[0];
  const void* wq = d_in[1];
  const void* bq = d_in[2];
  const void* wk = d_in[3];
  const void* bk = d_in[4];
  const void* wv = d_in[5];
  const void* bv = d_in[6];
  const void* wo = d_in[7];
  const int* pos = (const int*)d_in[8];

  const int S = 2048, H = 2048, KV = 512;
  const int B = in_sizes[0] / (S * H);
  const int M = B * S;

  char* ws = (char*)d_ws;
  size_t off = 0;
  auto alloc = [&](size_t bytes) { char* p = ws + off; off += (bytes + 255) & ~(size_t)255; return p; };
  bf16* hsb = (bf16*)alloc((size_t)M * H * 2);
  bf16* wqb = (bf16*)alloc((size_t)H * H * 2);
  bf16* wkb = (bf16*)alloc((size_t)KV * H * 2);
  bf16* wvb = (bf16*)alloc((size_t)KV * H * 2);
  bf16* wob = (bf16*)alloc((size_t)H * H * 2);
  bf16* bias3 = (bf16*)alloc(3072 * 2);
  bf16* Qb = (bf16*)alloc((size_t)M * H * 2);
  bf16* Kb = (bf16*)alloc((size_t)M * KV * 2);
  bf16* Vt = (bf16*)alloc((size_t)M * KV * 2);
  int* flag = (int*)alloc(256);
  bf16* AO = Qb;  // flash writes O over its own Q rows (disjoint per block)

  dtype_sniff<<<1, 256, 0, stream>>>((const unsigned int*)hs, flag);
  conv_all<<<2048, 256, 0, stream>>>(hs, wq, wk, wv, wo, bq, bk, bv,
                                     hsb, wqb, wkb, wvb, wob, bias3,
                                     (long)M * H / 4, flag);
  qkv_gemm<<<dim3(24, M / 128), 256, 0, stream>>>(hsb, wqb, wkb, wvb, bias3,
                                                  Qb, Kb, Vt, pos, M, H, S);
  flash_attn<<<dim3(B * 16, S / 128), 256, 0, stream>>>(Qb, Kb, Vt, AO, S);
  gemm_o<<<dim3(H / 128, M / 128), 256, 0, stream>>>(AO, wob, d_out, M, H, H, flag);
}

// Round 8
// 323.526 us; speedup vs baseline: 1.0885x; 1.0885x over previous
//
#include <hip/hip_runtime.h>
#include <hip/hip_bf16.h>
#include <math.h>

typedef __hip_bfloat16 bf16;
typedef __attribute__((ext_vector_type(8))) short short8;
typedef __attribute__((ext_vector_type(4))) float floatx4;
typedef __attribute__((ext_vector_type(16))) float floatx16;

__device__ __forceinline__ void async_copy16(const void* gptr, void* lptr) {
  __builtin_amdgcn_global_load_lds(
      (const __attribute__((address_space(1))) unsigned int*)gptr,
      (__attribute__((address_space(3))) unsigned int*)lptr,
      16, 0, 0);
}

__device__ __forceinline__ unsigned int f2bf_bits(float x) {
  bf16 h = __float2bfloat16(x);
  return (unsigned int)*reinterpret_cast<unsigned short*>(&h);
}

__device__ __forceinline__ float bfbits2f(unsigned int u) {
  unsigned v = u << 16;
  return *reinterpret_cast<float*>(&v);
}

__device__ __forceinline__ floatx4 mfma16(short8 a, short8 b, floatx4 c) {
  return __builtin_amdgcn_mfma_f32_16x16x32_bf16(a, b, c, 0, 0, 0);
}

// flag = 1 -> fp32 inputs, 0 -> bf16 inputs.
__global__ void dtype_sniff(const unsigned int* __restrict__ u, int* __restrict__ flag) {
  __shared__ int cnt[256];
  const int tid = threadIdx.x;
  const unsigned v = u[tid * 16];
  const int e = (v >> 7) & 0xFF;
  cnt[tid] = (e >= 90 && e <= 140) ? 1 : 0;
  __syncthreads();
  for (int s = 128; s > 0; s >>= 1) {
    if (tid < s) cnt[tid] += cnt[tid + s];
    __syncthreads();
  }
  if (tid == 0) flag[0] = (cnt[0] >= 192) ? 0 : 1;
}

// One kernel converting all inputs to bf16 (fp32 src if *flag else bf16 copy).
__global__ void conv_all(const void* hs, const void* wq, const void* wk, const void* wv,
                         const void* wo, const void* bq, const void* bk, const void* bv,
                         bf16* hsb, bf16* wqb, bf16* wkb, bf16* wvb, bf16* wob, bf16* b3,
                         long nhs4, const int* __restrict__ flag) {
  const bool f = (*flag != 0);
  const long W4 = 1048576, KV4 = 262144;  // H*H/4, KV*H/4
  const long total = nhs4 + W4 + 2 * KV4 + W4 + 512 + 128 + 128;
  const long stride = (long)gridDim.x * blockDim.x;
  for (long i = (long)blockIdx.x * blockDim.x + threadIdx.x; i < total; i += stride) {
    const void* src;
    bf16* dst;
    long off, j = i;
    if (j < nhs4) { src = hs; dst = hsb; off = j; }
    else if ((j -= nhs4) < W4) { src = wq; dst = wqb; off = j; }
    else if ((j -= W4) < KV4) { src = wk; dst = wkb; off = j; }
    else if ((j -= KV4) < KV4) { src = wv; dst = wvb; off = j; }
    else if ((j -= KV4) < W4) { src = wo; dst = wob; off = j; }
    else if ((j -= W4) < 512) { src = bq; dst = b3; off = j; }
    else if ((j -= 512) < 128) { src = bk; dst = b3 + 2048; off = j; }
    else { j -= 128; src = bv; dst = b3 + 2560; off = j; }
    uint2 o;
    if (f) {
      float4 v = ((const float4*)src)[off];
      o.x = f2bf_bits(v.x) | (f2bf_bits(v.y) << 16);
      o.y = f2bf_bits(v.z) | (f2bf_bits(v.w) << 16);
    } else {
      o = ((const uint2*)src)[off];
    }
    ((uint2*)dst)[off] = o;
  }
}

// ---------------------------------------------------------------------------
// m97-structure 128x128 GEMM core (4 waves, 256 thr), BK=64 (R5-verified).
// T3 "minimum 2-phase" double-buffer:
//   prologue: STAGE(buf0, t0); __syncthreads (drain+barrier)
//   loop t:   STAGE(buf^1, t+1)  -- flies under the MFMA cluster
//             ds_read buf[cur]; 32x MFMA
//             __syncthreads      -- vmcnt(0)+lgkmcnt(0)+barrier
// 16B k-slots XOR-swizzled (physical = logical ^ (row&7)); linear LDS dest +
// inverse-swizzled global source + swizzled ds_read (rule #21).
// R8: qkv grid transposed (m on blockIdx.x).  Consecutive blocks now share
// the W n-panel and walk A m-panels; per-XCD L2 working set ~2-3 MB (fits
// 4 MB) instead of all of A (16 MB).  Pure index remap.
// R7 lesson: BK=32 doubles barrier drains, no occupancy gain -> keep BK=64.
// ---------------------------------------------------------------------------

// Fused QKV GEMM + RoPE.  Q->Qb [M,2048] (rotated), K->Kb [M,512] (rotated),
// V->Vt [B,4,128,S] transposed.  bias3 = bq|bk|bv.
__global__ __launch_bounds__(256) void qkv_gemm(const bf16* __restrict__ A,
                                                const bf16* __restrict__ wq,
                                                const bf16* __restrict__ wk,
                                                const bf16* __restrict__ wv,
                                                const bf16* __restrict__ bias3,
                                                bf16* __restrict__ Qb,
                                                bf16* __restrict__ Kb,
                                                bf16* __restrict__ Vt,
                                                const int* __restrict__ pos_ids,
                                                int M, int K, int S) {
  __shared__ __align__(16) short lA[2 * 8192];  // 2 x 16 KB
  __shared__ __align__(16) short lB[2 * 8192];  // 2 x 16 KB
  const int tid = threadIdx.x;
  const int wave = tid >> 6;
  const int lane = tid & 63;
  const int lrow = lane & 15;
  const int quad = lane >> 4;
  const int m0 = blockIdx.x * 128;  // R8: m fastest
  const int n0 = blockIdx.y * 128;
  const int wm = (wave & 1) * 64;
  const int wn = (wave >> 1) * 64;
  const int srow = tid >> 3;   // [0,32) staging row within pass
  const int sslot = tid & 7;   // 16B k-slot

  const bf16* Wr;
  int nloc;
  if (n0 < 2048) { Wr = wq; nloc = n0; }
  else if (n0 < 2560) { Wr = wk; nloc = n0 - 2048; }
  else { Wr = wv; nloc = n0 - 2560; }

  auto stage = [&](int buf, int k0) {
#pragma unroll
    for (int p = 0; p < 4; ++p) {
      const int row = p * 32 + srow;
      const int gk = k0 + ((sslot ^ (row & 7)) << 3);  // inverse-swizzled src
      async_copy16(A + (size_t)(m0 + row) * K + gk,
                   &lA[buf * 8192 + p * 2048 + wave * 512]);
      async_copy16(Wr + (size_t)(nloc + row) * K + gk,
                   &lB[buf * 8192 + p * 2048 + wave * 512]);
    }
  };

  const int nt = K >> 6;
  floatx4 acc[4][4] = {};

  stage(0, 0);
  __syncthreads();
  for (int t = 0; t < nt; ++t) {
    const int cur = t & 1;
    if (t + 1 < nt) stage(cur ^ 1, (t + 1) << 6);
    const short* sA = &lA[cur * 8192];
    const short* sB = &lB[cur * 8192];
#pragma unroll
    for (int kap = 0; kap < 2; ++kap) {
      short8 af[4], bfr[4];
#pragma unroll
      for (int i = 0; i < 4; ++i) {
        const int R = wm + i * 16 + lrow;
        af[i] = *(const short8*)&sA[R * 64 + (((kap * 4 + quad) ^ (R & 7)) << 3)];
      }
#pragma unroll
      for (int j = 0; j < 4; ++j) {
        const int R = wn + j * 16 + lrow;
        bfr[j] = *(const short8*)&sB[R * 64 + (((kap * 4 + quad) ^ (R & 7)) << 3)];
      }
#pragma unroll
      for (int i = 0; i < 4; ++i)
#pragma unroll
        for (int j = 0; j < 4; ++j)
          acc[i][j] = mfma16(af[i], bfr[j], acc[i][j]);
    }
    __syncthreads();  // drains t+1 staging; buf[cur] fully consumed
  }

  if (n0 < 2560) {
    // Q or K: fused RoPE.  Partner wave = wave^2 (wn flipped by 64).
    short* exch = lA;
    const int myid = wave * 64 + lane;
    const int pid = (wave ^ 2) * 64 + lane;
    float pos[16];
#pragma unroll
    for (int i = 0; i < 4; ++i)
#pragma unroll
      for (int r = 0; r < 4; ++r)
        pos[i * 4 + r] = (float)pos_ids[m0 + wm + i * 16 + quad * 4 + r];
#pragma unroll
    for (int j = 0; j < 4; ++j) {
      const int col = n0 + wn + j * 16 + lrow;
      const float bv = __bfloat162float(bias3[col]);
      unsigned ob[16];
#pragma unroll
      for (int i = 0; i < 4; ++i)
#pragma unroll
        for (int r = 0; r < 4; ++r)
          ob[i * 4 + r] = f2bf_bits(acc[i][j][r] + bv);
      __syncthreads();  // previous round's reads (or main loop) done
#pragma unroll
      for (int k = 0; k < 4; ++k) {
        uint2 w;
        w.x = ob[4 * k + 0] | (ob[4 * k + 1] << 16);
        w.y = ob[4 * k + 2] | (ob[4 * k + 3] << 16);
        *(uint2*)&exch[myid * 20 + k * 4] = w;
      }
      __syncthreads();
      unsigned pb[16];
#pragma unroll
      for (int k = 0; k < 4; ++k) {
        const uint2 w = *(const uint2*)&exch[pid * 20 + k * 4];
        pb[4 * k + 0] = w.x & 0xffff; pb[4 * k + 1] = w.x >> 16;
        pb[4 * k + 2] = w.y & 0xffff; pb[4 * k + 3] = w.y >> 16;
      }
      const int d = col & 127;
      const float fr = exp2f((float)(d & 63) * -0.31143075889569023f);
      const float sgn = (d < 64) ? -1.0f : 1.0f;
      bf16* dst;
      int ldc, ccol;
      if (n0 < 2048) { dst = Qb; ldc = 2048; ccol = col; }
      else { dst = Kb; ldc = 512; ccol = col - 2048; }
#pragma unroll
      for (int i = 0; i < 4; ++i)
#pragma unroll
        for (int r = 0; r < 4; ++r) {
          float sn, cs;
          __sincosf(pos[i * 4 + r] * fr, &sn, &cs);
          const float v = bfbits2f(ob[i * 4 + r]);
          const float pv = bfbits2f(pb[i * 4 + r]);
          const int row = m0 + wm + i * 16 + quad * 4 + r;
          dst[(size_t)row * ldc + ccol] = __float2bfloat16(v * cs + sgn * pv * sn);
        }
    }
  } else {
    // V path: bias + transpose-store, no RoPE.
#pragma unroll
    for (int j = 0; j < 4; ++j) {
      const int col = n0 + wn + j * 16 + lrow;
      const float bv = __bfloat162float(bias3[col]);
#pragma unroll
      for (int i = 0; i < 4; ++i) {
        const int row = m0 + wm + i * 16 + quad * 4;
        const int dcol = col - 2560;
        const int kvh = dcol >> 7, d = dcol & 127;
        const int bb = row / S, s = row % S;
        uint2 pk;
        pk.x = f2bf_bits(acc[i][j][0] + bv) | (f2bf_bits(acc[i][j][1] + bv) << 16);
        pk.y = f2bf_bits(acc[i][j][2] + bv) | (f2bf_bits(acc[i][j][3] + bv) << 16);
        *(uint2*)&Vt[((size_t)(bb * 4 + kvh) * 128 + d) * S + s] = pk;
      }
    }
  }
}

// O-proj GEMM (same 2-phase BK=64 core): out fp32 if *flag else bf16.
__global__ __launch_bounds__(256) void gemm_o(const bf16* __restrict__ A,
                                              const bf16* __restrict__ W,
                                              void* __restrict__ C,
                                              int M, int N, int K,
                                              const int* __restrict__ flag) {
  __shared__ __align__(16) short lA[2 * 8192];
  __shared__ __align__(16) short lB[2 * 8192];
  const int tid = threadIdx.x;
  const int wave = tid >> 6;
  const int lane = tid & 63;
  const int lrow = lane & 15;
  const int quad = lane >> 4;
  const int m0 = blockIdx.y * 128;
  const int n0 = blockIdx.x * 128;
  const int wm = (wave & 1) * 64;
  const int wn = (wave >> 1) * 64;
  const int srow = tid >> 3;
  const int sslot = tid & 7;
  const bool of32 = (*flag != 0);

  auto stage = [&](int buf, int k0) {
#pragma unroll
    for (int p = 0; p < 4; ++p) {
      const int row = p * 32 + srow;
      const int gk = k0 + ((sslot ^ (row & 7)) << 3);
      async_copy16(A + (size_t)(m0 + row) * K + gk,
                   &lA[buf * 8192 + p * 2048 + wave * 512]);
      async_copy16(W + (size_t)(n0 + row) * K + gk,
                   &lB[buf * 8192 + p * 2048 + wave * 512]);
    }
  };

  const int nt = K >> 6;
  floatx4 acc[4][4] = {};

  stage(0, 0);
  __syncthreads();
  for (int t = 0; t < nt; ++t) {
    const int cur = t & 1;
    if (t + 1 < nt) stage(cur ^ 1, (t + 1) << 6);
    const short* sA = &lA[cur * 8192];
    const short* sB = &lB[cur * 8192];
#pragma unroll
    for (int kap = 0; kap < 2; ++kap) {
      short8 af[4], bfr[4];
#pragma unroll
      for (int i = 0; i < 4; ++i) {
        const int R = wm + i * 16 + lrow;
        af[i] = *(const short8*)&sA[R * 64 + (((kap * 4 + quad) ^ (R & 7)) << 3)];
      }
#pragma unroll
      for (int j = 0; j < 4; ++j) {
        const int R = wn + j * 16 + lrow;
        bfr[j] = *(const short8*)&sB[R * 64 + (((kap * 4 + quad) ^ (R & 7)) << 3)];
      }
#pragma unroll
      for (int i = 0; i < 4; ++i)
#pragma unroll
        for (int j = 0; j < 4; ++j)
          acc[i][j] = mfma16(af[i], bfr[j], acc[i][j]);
    }
    __syncthreads();
  }

#pragma unroll
  for (int j = 0; j < 4; ++j) {
    const int col = n0 + wn + j * 16 + lrow;
#pragma unroll
    for (int i = 0; i < 4; ++i) {
      const int row = m0 + wm + i * 16 + quad * 4;
#pragma unroll
      for (int r = 0; r < 4; ++r) {
        const size_t idx = (size_t)(row + r) * N + col;
        if (of32) ((float*)C)[idx] = acc[i][j][r];
        else ((bf16*)C)[idx] = __float2bfloat16(acc[i][j][r]);
      }
    }
  }
}

// Flash attention, 32x32x16 MFMA, single-barrier double-buffered pipeline.
// Block = 128 q x one (b,h); 4 waves, wave owns 32 q-cols.  BKV=64.
// K/V fragment-order staging (HW-verified layouts).  Q in registers.
// qt pairing (y<8 ? y : 23-y) balances per-CU work under mod-256 round-robin
// dispatch: resident pairs (qt, 15-qt) sum to 36 iters each.
// P kept in-register (T12) via v_permlane32_swap_b32; defer-rescale THR=0.
// (R5-exact source -- best measured config.)
__global__ __launch_bounds__(256, 2) void flash_attn(const bf16* Q,
                                                     const bf16* __restrict__ K,
                                                     const bf16* __restrict__ Vt,
                                                     bf16* O, int S) {
  __shared__ __align__(16) short lK[2][16 * 512];  // 2 x 16 KB
  __shared__ __align__(16) short lV[2][16 * 512];  // 2 x 16 KB

  const int tid = threadIdx.x;
  const int wave = tid >> 6;
  const int lane = tid & 63;
  const int l31 = lane & 31;
  const int half = lane >> 5;
  const int bh = blockIdx.x;
  const int y = blockIdx.y;
  const int qt = (y < 8) ? y : 23 - y;
  const int q0 = qt * 128;
  const int b = bh >> 4;
  const int h = bh & 15;
  const int kvh = h >> 2;
  const int wq0 = wave * 32;
  const int q_g = q0 + wq0 + l31;

  short8 qf[8];
  {
    const bf16* qbase = Q + ((size_t)(b * S + q_g) * 16 + h) * 128 + half * 8;
#pragma unroll
    for (int ks = 0; ks < 8; ++ks)
      qf[ks] = *(const short8*)(qbase + ks * 16);
  }

  floatx16 acc[4] = {};
  float m_i = -1.0e30f, l_i = 0.0f;
  const float scale = 0.08838834764831845f;
  const int fk0 = wave * 4;
  const int niter = 2 * qt + 2;

  auto stage = [&](int buf, int kv0) {
#pragma unroll
    for (int i = 0; i < 4; ++i) {
      const int fk = fk0 + i;
      const int mt = fk & 1, kstep = fk >> 1;
      async_copy16(K + ((size_t)(b * S + kv0 + mt * 32 + l31) * 4 + kvh) * 128 + kstep * 16 + half * 8,
                   &lK[buf][fk * 512]);
      const int kvs = fk >> 2, mtd = fk & 3;
      async_copy16(Vt + ((size_t)(b * 4 + kvh) * 128 + mtd * 32 + l31) * S + kv0 + kvs * 16 + half * 8,
                   &lV[buf][fk * 512]);
    }
  };

  stage(0, 0);  // prefetch

  for (int it = 0; it < niter; ++it) {
    const int kv0 = it * 64;
    const int cur = it & 1;
    __syncthreads();  // drains DMA(cur) issued one iter ago; frees buf cur^1
    if (it + 1 < niter) stage(cur ^ 1, kv0 + 64);

    // S^T = K·Q^T  (C: col = q = l31, row = kv = mt*32 + (r&3)+8*(r>>2)+4*half)
    floatx16 st[2] = {};
#pragma unroll
    for (int ks = 0; ks < 8; ++ks) {
      short8 k0 = *(const short8*)&lK[cur][(ks * 2 + 0) * 512 + lane * 8];
      short8 k1 = *(const short8*)&lK[cur][(ks * 2 + 1) * 512 + lane * 8];
      st[0] = __builtin_amdgcn_mfma_f32_32x32x16_bf16(k0, qf[ks], st[0], 0, 0, 0);
      st[1] = __builtin_amdgcn_mfma_f32_32x32x16_bf16(k1, qf[ks], st[1], 0, 0, 0);
    }

    float mx = -1.0e30f;
    if (kv0 + 63 > q0 + wq0) {
#pragma unroll
      for (int r = 0; r < 16; ++r) {
        const int kv_l = kv0 + (r & 3) + 8 * (r >> 2) + 4 * half;
        float v0 = st[0][r] * scale;
        v0 = (kv_l > q_g) ? -1.0e9f : v0;
        float v1 = st[1][r] * scale;
        v1 = (kv_l + 32 > q_g) ? -1.0e9f : v1;
        st[0][r] = v0; st[1][r] = v1;
        mx = fmaxf(mx, fmaxf(v0, v1));
      }
    } else {
#pragma unroll
      for (int r = 0; r < 16; ++r) {
        const float v0 = st[0][r] * scale;
        const float v1 = st[1][r] * scale;
        st[0][r] = v0; st[1][r] = v1;
        mx = fmaxf(mx, fmaxf(v0, v1));
      }
    }
    mx = fmaxf(mx, __shfl_xor(mx, 32));
    if (!__all(mx <= m_i)) {  // defer-rescale THR=0 (bit-identical)
      const float mnew = fmaxf(m_i, mx);
      const float alpha = __expf(m_i - mnew);
      m_i = mnew;
      l_i *= alpha;
#pragma unroll
      for (int t = 0; t < 4; ++t)
#pragma unroll
        for (int r = 0; r < 16; ++r) acc[t][r] *= alpha;
    }
    float rs = 0.0f;
#pragma unroll
    for (int r = 0; r < 16; ++r) {
      const float p0 = __expf(st[0][r] - m_i);
      const float p1 = __expf(st[1][r] - m_i);
      st[0][r] = p0; st[1][r] = p1;
      rs += p0 + p1;
    }
    rs += __shfl_xor(rs, 32);
    l_i += rs;

    // P -> PV B-fragments in-register (T12) via v_permlane32_swap_b32.
#pragma unroll
    for (int kvs = 0; kvs < 4; ++kvs) {
      const int cLo = 2 * kvs, cHi = cLo + 1;
      const int mtL = cLo >> 2, gL = cLo & 3;
      const int mtH = cHi >> 2, gH = cHi & 3;
      unsigned a0 = f2bf_bits(st[mtL][4 * gL + 0]) | (f2bf_bits(st[mtL][4 * gL + 1]) << 16);
      unsigned a1 = f2bf_bits(st[mtL][4 * gL + 2]) | (f2bf_bits(st[mtL][4 * gL + 3]) << 16);
      unsigned b0 = f2bf_bits(st[mtH][4 * gH + 0]) | (f2bf_bits(st[mtH][4 * gH + 1]) << 16);
      unsigned b1 = f2bf_bits(st[mtH][4 * gH + 2]) | (f2bf_bits(st[mtH][4 * gH + 3]) << 16);
      asm("v_permlane32_swap_b32 %0, %1" : "+v"(a0), "+v"(b0));
      asm("v_permlane32_swap_b32 %0, %1" : "+v"(a1), "+v"(b1));
      union { unsigned u[4]; short8 s; } pu;
      pu.u[0] = a0; pu.u[1] = a1; pu.u[2] = b0; pu.u[3] = b1;
      const short8 pf = pu.s;
#pragma unroll
      for (int mtd = 0; mtd < 4; ++mtd) {
        short8 vf = *(const short8*)&lV[cur][(kvs * 4 + mtd) * 512 + lane * 8];
        acc[mtd] = __builtin_amdgcn_mfma_f32_32x32x16_bf16(vf, pf, acc[mtd], 0, 0, 0);
      }
    }
  }

  const float inv_l = 1.0f / l_i;
  bf16* obase = O + ((size_t)(b * S + q_g) * 16 + h) * 128;
#pragma unroll
  for (int mtd = 0; mtd < 4; ++mtd)
#pragma unroll
    for (int g = 0; g < 4; ++g) {
      uint2 pk;
      pk.x = f2bf_bits(acc[mtd][4 * g] * inv_l) | (f2bf_bits(acc[mtd][4 * g + 1] * inv_l) << 16);
      pk.y = f2bf_bits(acc[mtd][4 * g + 2] * inv_l) | (f2bf_bits(acc[mtd][4 * g + 3] * inv_l) << 16);
      *(uint2*)(obase + mtd * 32 + 8 * g + 4 * half) = pk;
    }
}

extern "C" void kernel_launch(void* const* d_in, const int* in_sizes, int n_in,
                              void* d_out, int out_size, void* d_ws, size_t ws_size,
                              hipStream_t stream) {
  const void* hs = d_in[0];
  const void* wq = d_in[1];
  const void* bq = d_in[2];
  const void* wk = d_in[3];
  const void* bk = d_in[4];
  const void* wv = d_in[5];
  const void* bv = d_in[6];
  const void* wo = d_in[7];
  const int* pos = (const int*)d_in[8];

  const int S = 2048, H = 2048, KV = 512;
  const int B = in_sizes[0] / (S * H);
  const int M = B * S;

  char* ws = (char*)d_ws;
  size_t off = 0;
  auto alloc = [&](size_t bytes) { char* p = ws + off; off += (bytes + 255) & ~(size_t)255; return p; };
  bf16* hsb = (bf16*)alloc((size_t)M * H * 2);
  bf16* wqb = (bf16*)alloc((size_t)H * H * 2);
  bf16* wkb = (bf16*)alloc((size_t)KV * H * 2);
  bf16* wvb = (bf16*)alloc((size_t)KV * H * 2);
  bf16* wob = (bf16*)alloc((size_t)H * H * 2);
  bf16* bias3 = (bf16*)alloc(3072 * 2);
  bf16* Qb = (bf16*)alloc((size_t)M * H * 2);
  bf16* Kb = (bf16*)alloc((size_t)M * KV * 2);
  bf16* Vt = (bf16*)alloc((size_t)M * KV * 2);
  int* flag = (int*)alloc(256);
  bf16* AO = Qb;  // flash writes O over its own Q rows (disjoint per block)

  dtype_sniff<<<1, 256, 0, stream>>>((const unsigned int*)hs, flag);
  conv_all<<<2048, 256, 0, stream>>>(hs, wq, wk, wv, wo, bq, bk, bv,
                                     hsb, wqb, wkb, wvb, wob, bias3,
                                     (long)M * H / 4, flag);
  qkv_gemm<<<dim3(M / 128, 24), 256, 0, stream>>>(hsb, wqb, wkb, wvb, bias3,
                                                  Qb, Kb, Vt, pos, M, H, S);
  flash_attn<<<dim3(B * 16, S / 128), 256, 0, stream>>>(Qb, Kb, Vt, AO, S);
  gemm_o<<<dim3(H / 128, M / 128), 256, 0, stream>>>(AO, wob, d_out, M, H, H, flag);
}